// Round 2
// baseline (2426.676 us; speedup 1.0000x reference)
//
#include <hip/hip_runtime.h>
#include <hip/hip_fp16.h>

// BEiT-style attention block. fp32 GEMM compute; K/V/O stored fp16 to fit ws.
//   B=128 N=197 C=768 H=12 d=64, M = B*N = 25216 = 197*128 (tiles divide exactly)
// Pipeline:
//   k0: rpb[h][i][j] = table[rel_index[i][j]][h]          (fp32, 1.9 MB)
//   k1: qkv GEMM (M x 768)@(2304 x 768)^T -> q(fp32, scaled) into d_out,
//       k/v (fp16) into ws, bitfit bias added            [B,H,N,64]
//   k2: flash attention per (b,h): q/o in VGPRs, K/V fp16 uniform loads,
//       O (fp16) -> ws in [B,N,C]
//   k3: proj GEMM (M x 768 fp16)@(768 x 768)^T + b_proj -> d_out (fp32)
// Workspace: 3 * 38.7MB (k,v,O fp16) + 1.9MB (rpb) ~= 118 MB. q lives in d_out
// (dead before k3 overwrites d_out). Everything rewritten every launch.

#define B_   128
#define N_   197
#define C_   768
#define H_   12
#define HD_  64
#define M_   (B_ * N_)        // 25216
#define NREL (N_ * N_)        // 38809
#define LDS_STRIDE 144        // 128 + swizzle headroom (max 139), float4-aligned

// ---------------- k0: relative-position-bias gather ----------------
__global__ __launch_bounds__(256) void rpb_kernel(
    const float* __restrict__ table, const int* __restrict__ ridx,
    float* __restrict__ rpb)
{
    int g = blockIdx.x * 256 + threadIdx.x;
    if (g >= NREL) return;
    int r = ridx[g];
    #pragma unroll
    for (int h = 0; h < H_; ++h)
        rpb[h * NREL + g] = table[r * H_ + h];
}

// ---------------- 16-element row loaders (fp32 LDS staging) ----------------
__device__ __forceinline__ void load16(const float* __restrict__ p, float* v) {
    #pragma unroll
    for (int c = 0; c < 4; ++c) {
        const float4 t = *(const float4*)(p + 4 * c);
        v[4*c+0] = t.x; v[4*c+1] = t.y; v[4*c+2] = t.z; v[4*c+3] = t.w;
    }
}
__device__ __forceinline__ void load16(const __half* __restrict__ p, float* v) {
    #pragma unroll
    for (int c = 0; c < 2; ++c) {
        const float4 t = *(const float4*)(p + 8 * c);   // 8 halfs
        const __half2* h2 = (const __half2*)&t;
        #pragma unroll
        for (int j = 0; j < 4; ++j) {
            const float2 f = __half22float2(h2[j]);
            v[8*c + 2*j + 0] = f.x;
            v[8*c + 2*j + 1] = f.y;
        }
    }
}

// ---------------- GEMM: C[m][n] = sum_k A[m][k] * W[n][k] ----------------
// MODE 0 (AT=float): qkv proj -> q fp32 (scaled) + k/v fp16, per-sample bias
// MODE 1 (AT=half):  out proj -> d_out fp32 + b_proj[b_idx]
// BM=BN=128, BK=32, 256 threads, 8x8 register block. LDS k-major, column
// swizzle p(c)=c+4*(c>>5) so fragment ds_read_b128 is 2-way (free).
template<int MODE, typename AT>
__global__ __launch_bounds__(256) void gemm_kernel(
    const AT*    __restrict__ A,      // [M, 768]
    const float* __restrict__ W,      // [Ncols, 768] (output col = W row)
    const int*   __restrict__ b_idx,  // [B]
    const float* __restrict__ bias0,  // MODE0: q_bias, MODE1: b_proj
    const float* __restrict__ bias1,  // MODE0: k_bias
    const float* __restrict__ bias2,  // MODE0: v_bias
    float*  __restrict__ outF,        // MODE0: q (d_out scratch), MODE1: d_out
    __half* __restrict__ outK,        // MODE0: k
    __half* __restrict__ outV)        // MODE0: v
{
    __shared__ float As[32 * LDS_STRIDE];
    __shared__ float Bs[32 * LDS_STRIDE];

    const int t   = threadIdx.x;
    const int m0  = blockIdx.x * 128;
    const int n0  = blockIdx.y * 128;
    const int row = t >> 1;            // 0..127
    const int kf  = (t & 1) * 16;      // 16-wide k-slice
    const int tx  = t & 15;
    const int ty  = t >> 4;
    const int prow = row + ((row >> 5) << 2);   // swizzled LDS column

    const AT*    aptr = A + (size_t)(m0 + row) * C_ + kf;
    const float* bptr = W + (size_t)(n0 + row) * C_ + kf;

    float pav[16], pbv[16];
    load16(aptr, pav);
    load16(bptr, pbv);

    float acc[8][8] = {};
    const int aoff = ty * 8 + ((ty >> 2) << 2);  // = p(ty*8)
    const int boff = tx * 8 + ((tx >> 2) << 2);  // = p(tx*8)

    for (int kt = 0; kt < C_; kt += 32) {
        __syncthreads();   // previous tile's compute done
        #pragma unroll
        for (int c = 0; c < 16; ++c) {
            As[(kf + c) * LDS_STRIDE + prow] = pav[c];
            Bs[(kf + c) * LDS_STRIDE + prow] = pbv[c];
        }
        __syncthreads();
        if (kt + 32 < C_) {          // register-prefetch next k-tile
            load16(aptr + kt + 32, pav);
            load16(bptr + kt + 32, pbv);
        }
        #pragma unroll 8
        for (int kk = 0; kk < 32; ++kk) {
            const float4 a0 = *(const float4*)&As[kk * LDS_STRIDE + aoff];
            const float4 a1 = *(const float4*)&As[kk * LDS_STRIDE + aoff + 4];
            const float4 b0 = *(const float4*)&Bs[kk * LDS_STRIDE + boff];
            const float4 b1 = *(const float4*)&Bs[kk * LDS_STRIDE + boff + 4];
            const float ar[8] = {a0.x, a0.y, a0.z, a0.w, a1.x, a1.y, a1.z, a1.w};
            const float br[8] = {b0.x, b0.y, b0.z, b0.w, b1.x, b1.y, b1.z, b1.w};
            #pragma unroll
            for (int i = 0; i < 8; ++i)
                #pragma unroll
                for (int j = 0; j < 8; ++j)
                    acc[i][j] = fmaf(ar[i], br[j], acc[i][j]);
        }
    }

    if (MODE == 0) {
        const int part = (n0 >= 2 * C_) ? 2 : (n0 >= C_) ? 1 : 0;  // q/k/v
        const int cip  = (n0 - part * C_) + tx * 8;
        const int h    = cip >> 6;
        const int d0   = cip & 63;
        if (part == 0) {
            #pragma unroll
            for (int i = 0; i < 8; ++i) {
                const int m = m0 + ty * 8 + i;
                const int b = m / N_;
                const int n = m - b * N_;
                const int s = b_idx[b];
                const float* bb = bias0 + s * C_ + h * HD_ + d0;
                float* op = outF + ((size_t)((b * H_ + h) * N_ + n)) * HD_ + d0;
                float4 r0, r1;
                r0.x = (acc[i][0] + bb[0]) * 0.125f;
                r0.y = (acc[i][1] + bb[1]) * 0.125f;
                r0.z = (acc[i][2] + bb[2]) * 0.125f;
                r0.w = (acc[i][3] + bb[3]) * 0.125f;
                r1.x = (acc[i][4] + bb[4]) * 0.125f;
                r1.y = (acc[i][5] + bb[5]) * 0.125f;
                r1.z = (acc[i][6] + bb[6]) * 0.125f;
                r1.w = (acc[i][7] + bb[7]) * 0.125f;
                *(float4*)op = r0;
                *(float4*)(op + 4) = r1;
            }
        } else {
            const float* bias = (part == 1) ? bias1 : bias2;
            __half* outp = (part == 1) ? outK : outV;
            #pragma unroll
            for (int i = 0; i < 8; ++i) {
                const int m = m0 + ty * 8 + i;
                const int b = m / N_;
                const int n = m - b * N_;
                const int s = b_idx[b];
                const float* bb = bias + s * C_ + h * HD_ + d0;
                __half* op = outp + ((size_t)((b * H_ + h) * N_ + n)) * HD_ + d0;
                __half2 hh[4];
                #pragma unroll
                for (int j = 0; j < 4; ++j)
                    hh[j] = __floats2half2_rn(acc[i][2*j] + bb[2*j],
                                              acc[i][2*j+1] + bb[2*j+1]);
                *(float4*)op = *(const float4*)hh;   // 8 halfs = 16B
            }
        }
    } else {
        const int col = n0 + tx * 8;
        #pragma unroll
        for (int i = 0; i < 8; ++i) {
            const int m = m0 + ty * 8 + i;
            const int b = m / N_;
            const int s = b_idx[b];
            const float* bb = bias0 + s * C_ + col;
            float* op = outF + (size_t)m * C_ + col;
            float4 r0, r1;
            r0.x = acc[i][0] + bb[0];  r0.y = acc[i][1] + bb[1];
            r0.z = acc[i][2] + bb[2];  r0.w = acc[i][3] + bb[3];
            r1.x = acc[i][4] + bb[4];  r1.y = acc[i][5] + bb[5];
            r1.z = acc[i][6] + bb[6];  r1.w = acc[i][7] + bb[7];
            *(float4*)op = r0;
            *(float4*)(op + 4) = r1;
        }
    }
}

// ---------------- k2: flash attention ----------------
// One block per (b,h); thread = one q row. K/V addresses are block-uniform
// -> scalarized loads broadcast to all lanes.
template<int CNT>
__device__ __forceinline__ void attn_chunk(
    const __half* __restrict__ kb, const __half* __restrict__ vb,
    const float* __restrict__ rp, int j0,
    const float* __restrict__ q, float* __restrict__ o, float& m, float& l)
{
    float s[CNT];
    #pragma unroll
    for (int jj = 0; jj < CNT; ++jj) {
        const __half2* kr = (const __half2*)(kb + (size_t)(j0 + jj) * HD_);
        float acc = 0.f;
        #pragma unroll
        for (int d2 = 0; d2 < HD_ / 2; ++d2) {
            const float2 kv = __half22float2(kr[d2]);
            acc = fmaf(q[2*d2], kv.x, acc);
            acc = fmaf(q[2*d2+1], kv.y, acc);
        }
        s[jj] = acc + rp[j0 + jj];
    }
    float cm = s[0];
    #pragma unroll
    for (int jj = 1; jj < CNT; ++jj) cm = fmaxf(cm, s[jj]);
    if (cm > m) {
        const float sc = __expf(m - cm);
        m = cm;
        l *= sc;
        #pragma unroll
        for (int d = 0; d < HD_; ++d) o[d] *= sc;
    }
    #pragma unroll
    for (int jj = 0; jj < CNT; ++jj) {
        const float p = __expf(s[jj] - m);
        l += p;
        s[jj] = p;
    }
    #pragma unroll
    for (int jj = 0; jj < CNT; ++jj) {
        const __half2* vr = (const __half2*)(vb + (size_t)(j0 + jj) * HD_);
        #pragma unroll
        for (int d2 = 0; d2 < HD_ / 2; ++d2) {
            const float2 vv = __half22float2(vr[d2]);
            o[2*d2]   = fmaf(s[jj], vv.x, o[2*d2]);
            o[2*d2+1] = fmaf(s[jj], vv.y, o[2*d2+1]);
        }
    }
}

__global__ __launch_bounds__(256) void attn_kernel(
    const float* __restrict__ qws, const __half* __restrict__ kws,
    const __half* __restrict__ vws, const float* __restrict__ rpb,
    __half* __restrict__ ows)
{
    const int bh = blockIdx.x;          // b*12 + h
    const int i  = threadIdx.x;
    if (i >= N_) return;
    const int b = bh / H_;
    const int h = bh - b * H_;

    const float* qp = qws + ((size_t)(bh * N_ + i)) * HD_;
    float q[HD_];
    #pragma unroll
    for (int c = 0; c < HD_ / 4; ++c) {
        const float4 v = *(const float4*)(qp + c * 4);
        q[c*4+0] = v.x; q[c*4+1] = v.y; q[c*4+2] = v.z; q[c*4+3] = v.w;
    }

    float o[HD_] = {};
    float m = -INFINITY, l = 0.f;
    const __half* kb = kws + (size_t)bh * N_ * HD_;
    const __half* vb = vws + (size_t)bh * N_ * HD_;
    const float*  rp = rpb + (size_t)h * NREL + (size_t)i * N_;

    int j0 = 0;
    for (int c = 0; c < 24; ++c, j0 += 8)          // 24*8 = 192
        attn_chunk<8>(kb, vb, rp, j0, q, o, m, l);
    attn_chunk<5>(kb, vb, rp, 192, q, o, m, l);    // tail 197-192

    const float inv = 1.f / l;
    __half* op = ows + ((size_t)(b * N_ + i)) * C_ + h * HD_;  // O in [B,N,C] fp16
    #pragma unroll
    for (int c = 0; c < HD_ / 8; ++c) {
        __half2 hh[4];
        #pragma unroll
        for (int j = 0; j < 4; ++j)
            hh[j] = __floats2half2_rn(o[c*8 + 2*j] * inv, o[c*8 + 2*j + 1] * inv);
        *(float4*)(op + c * 8) = *(const float4*)hh;
    }
}

// ---------------- launcher ----------------
extern "C" void kernel_launch(void* const* d_in, const int* in_sizes, int n_in,
                              void* d_out, int out_size, void* d_ws, size_t ws_size,
                              hipStream_t stream)
{
    const float* x      = (const float*)d_in[0];
    const int*   b_idx  = (const int*)  d_in[1];
    const float* w_qkv  = (const float*)d_in[2];
    const float* q_bias = (const float*)d_in[3];
    const float* k_bias = (const float*)d_in[4];
    const float* v_bias = (const float*)d_in[5];
    const float* table  = (const float*)d_in[6];
    const int*   ridx   = (const int*)  d_in[7];
    const float* w_proj = (const float*)d_in[8];
    const float* b_proj = (const float*)d_in[9];
    float* outF = (float*)d_out;                 // q scratch, then final output

    const size_t per = (size_t)B_ * H_ * N_ * HD_;   // 19,365,888 elements
    __half* kh  = (__half*)d_ws;                 // [B,H,N,64] fp16
    __half* vh  = kh + per;                      // [B,H,N,64] fp16
    __half* oh  = vh + per;                      // [B,N,C]    fp16
    float*  rpb = (float*)(oh + per);            // [H,N,N]    fp32
    // ws bytes: 3*per*2 + NREL*H*4  ~= 118 MB

    rpb_kernel<<<(NREL + 255) / 256, 256, 0, stream>>>(table, ridx, rpb);

    gemm_kernel<0, float><<<dim3(M_ / 128, 2304 / 128), 256, 0, stream>>>(
        x, w_qkv, b_idx, q_bias, k_bias, v_bias, outF, kh, vh);

    attn_kernel<<<B_ * H_, 256, 0, stream>>>(outF, kh, vh, rpb, oh);

    gemm_kernel<1, __half><<<dim3(M_ / 128, C_ / 128), 256, 0, stream>>>(
        oh, w_proj, b_idx, b_proj, nullptr, nullptr, outF, nullptr, nullptr);
}

// Round 4
// 612.701 us; speedup vs baseline: 3.9606x; 3.9606x over previous
//
#include <hip/hip_runtime.h>

// BEiT attention block on MFMA (gfx950). B=128 N=197 C=768 H=12 d=64.
// All GEMM-shaped work on v_mfma_f32_16x16x32_f16 (fp16 in, fp32 accum).
// Pipeline:
//   cvt      : x, w_qkv, w_proj -> fp16
//   rpbt     : rel-pos bias gathered to [h][j][i-pad200] fp16 (transposed for f16x4 loads)
//   gemm<0>  : qkv = xh @ wqkvh^T; epilogue: +bitfit bias, q*0.125 -> qh(d_out),
//              k -> kh [b,h,n,64], v -> vt [b,h,64,216] (transposed, padded)
//   attn     : flash per (b,h); wave = 64 q rows; KVBLK=64; K/V/rpb streamed from L2
//   gemm<1>  : out = oh @ wprojh^T + b_proj -> d_out (f32)
// ws layout (125.6 MB): [xh|oh overlay 38.7M][kh 38.7M][vt 42.5M][wqkvh][wprojh][rpbt]

typedef _Float16 f16;
typedef __attribute__((ext_vector_type(8))) _Float16 f16x8;
typedef __attribute__((ext_vector_type(4))) float f32x4;
#define MFMA16(a, b, c) __builtin_amdgcn_mfma_f32_16x16x32_f16(a, b, c, 0, 0, 0)

#define B_ 128
#define N_ 197
#define H_ 12
#define M_ (B_ * N_)   // 25216 = 197*128

// ---------------- fp32 -> fp16 convert (8 elems/thread) ----------------
__global__ __launch_bounds__(256) void cvt_kernel(
    const float* __restrict__ in, f16* __restrict__ out, int n8)
{
    int g = blockIdx.x * 256 + threadIdx.x;
    if (g >= n8) return;
    const float4 a = *(const float4*)(in + (size_t)g * 8);
    const float4 b = *(const float4*)(in + (size_t)g * 8 + 4);
    f16x8 o;
    o[0] = (f16)a.x; o[1] = (f16)a.y; o[2] = (f16)a.z; o[3] = (f16)a.w;
    o[4] = (f16)b.x; o[5] = (f16)b.y; o[6] = (f16)b.z; o[7] = (f16)b.w;
    *(f16x8*)(out + (size_t)g * 8) = o;
}

// ---------------- rpbt[h][j][i(pad 200)] = table[ridx[i][j]][h] ----------------
__global__ __launch_bounds__(256) void rpbt_kernel(
    const float* __restrict__ table, const int* __restrict__ ridx,
    f16* __restrict__ rpbt)
{
    int g = blockIdx.x * 256 + threadIdx.x;
    if (g >= 12 * 197 * 200) return;
    int h   = g / (197 * 200);
    int rem = g - h * 197 * 200;
    int j   = rem / 200;
    int i   = rem - j * 200;
    if (i > 196) i = 196;                      // pad = dup of last row (benign)
    rpbt[g] = (f16)table[ridx[i * 197 + j] * 12 + h];
}

// ---------------- MFMA GEMM: C[m][n] = sum_k A[m][k] * W[n][k] ----------------
// 128x128 tile, BK=32, 4 waves (2x2), per-wave 64x64 = 4x4 fragments 16x16.
// LDS [row][32 halfs] with XOR swizzle (slot ^ (row&3)) -> 2-way conflicts (free).
// MODE 0: A = xh [M][768]; outputs q (fp16,*0.125)+k natural, v transposed.
// MODE 1: A = oh in [b][h][n][64] layout; output f32 + b_proj.
template<int MODE>
__global__ __launch_bounds__(256) void mfma_gemm(
    const f16* __restrict__ A, const f16* __restrict__ W,
    const int* __restrict__ b_idx,
    const float* __restrict__ bq, const float* __restrict__ bk,
    const float* __restrict__ bv,
    f16* __restrict__ qo, f16* __restrict__ ko, f16* __restrict__ vo,
    float* __restrict__ fo, const float* __restrict__ bp)
{
    __shared__ alignas(16) f16 As[4096];
    __shared__ alignas(16) f16 Bs[4096];
    const int t = threadIdx.x, l = t & 63;
    const int w = t >> 6, wm = w >> 1, wn = w & 1;
    const int m0 = blockIdx.x * 128, n0 = blockIdx.y * 128;

    // staging: this thread owns chunks t and t+256 (512 x 16B per tile)
    const int sr0 = t >> 2, sr1 = sr0 + 64, ss = t & 3;
    const int wo0 = sr0 * 64 + ((ss ^ (sr0 & 3)) << 4);   // swizzled LDS byte offs
    const int wo1 = sr1 * 64 + ((ss ^ (sr1 & 3)) << 4);

    const f16* wr0 = W + (size_t)(n0 + sr0) * 768 + ss * 8;
    const f16* wr1 = W + (size_t)(n0 + sr1) * 768 + ss * 8;
    const f16* ar0 = A + (size_t)(m0 + sr0) * 768 + ss * 8;   // MODE 0 path
    const f16* ar1 = A + (size_t)(m0 + sr1) * 768 + ss * 8;
    int ab0 = 0, an0 = 0, ab1 = 0, an1 = 0;
    if (MODE == 1) {
        ab0 = (m0 + sr0) / 197; an0 = (m0 + sr0) - ab0 * 197;
        ab1 = (m0 + sr1) / 197; an1 = (m0 + sr1) - ab1 * 197;
    }
    auto aaddr = [&](int b, int n, int kt) -> const f16* {
        const int k0 = kt + ss * 8;     // h = k0>>6, d = k0&63
        return A + ((size_t)(b * 12 + (k0 >> 6)) * 197 + n) * 64 + (k0 & 63);
    };

    uint4 va0, va1, vb0, vb1;
    if (MODE == 0) { va0 = *(const uint4*)ar0; va1 = *(const uint4*)ar1; }
    else { va0 = *(const uint4*)aaddr(ab0, an0, 0); va1 = *(const uint4*)aaddr(ab1, an1, 0); }
    vb0 = *(const uint4*)wr0; vb1 = *(const uint4*)wr1;

    f32x4 acc[4][4] = {};
    int aoff[4], boff[4];
    #pragma unroll
    for (int i = 0; i < 4; ++i) {
        const int ar = wm * 64 + i * 16 + (l & 15);
        aoff[i] = ar * 64 + ((((l >> 4) * 16) ^ ((ar & 3) << 4)));
        const int br = wn * 64 + i * 16 + (l & 15);
        boff[i] = br * 64 + ((((l >> 4) * 16) ^ ((br & 3) << 4)));
    }

    for (int kt = 0; kt < 768; kt += 32) {
        __syncthreads();
        *(uint4*)((char*)As + wo0) = va0;
        *(uint4*)((char*)As + wo1) = va1;
        *(uint4*)((char*)Bs + wo0) = vb0;
        *(uint4*)((char*)Bs + wo1) = vb1;
        __syncthreads();
        if (kt + 32 < 768) {                       // prefetch next K-tile
            const int kn = kt + 32;
            if (MODE == 0) { va0 = *(const uint4*)(ar0 + kn); va1 = *(const uint4*)(ar1 + kn); }
            else { va0 = *(const uint4*)aaddr(ab0, an0, kn); va1 = *(const uint4*)aaddr(ab1, an1, kn); }
            vb0 = *(const uint4*)(wr0 + kn); vb1 = *(const uint4*)(wr1 + kn);
        }
        f16x8 af[4], bf[4];
        #pragma unroll
        for (int i = 0; i < 4; ++i) {
            af[i] = *(const f16x8*)((const char*)As + aoff[i]);
            bf[i] = *(const f16x8*)((const char*)Bs + boff[i]);
        }
        #pragma unroll
        for (int mi = 0; mi < 4; ++mi)
            #pragma unroll
            for (int nj = 0; nj < 4; ++nj)
                acc[mi][nj] = MFMA16(af[mi], bf[nj], acc[mi][nj]);
    }

    if (MODE == 0) {
        const int part = n0 / 768;                      // 0=q 1=k 2=v (block-uniform)
        const int hh = ((n0 % 768) + wn * 64) >> 6;     // head (wave-uniform)
        const float* bias = (part == 0) ? bq : (part == 1) ? bk : bv;
        #pragma unroll
        for (int mi = 0; mi < 4; ++mi) {
            #pragma unroll
            for (int r = 0; r < 4; ++r) {
                const int m = m0 + wm * 64 + mi * 16 + ((l >> 4) << 2) + r;
                const int b = m / 197, n = m - (m / 197) * 197;
                const int s = b_idx[b];
                #pragma unroll
                for (int nj = 0; nj < 4; ++nj) {
                    const int dd = nj * 16 + (l & 15);
                    const float v = acc[mi][nj][r] + bias[s * 768 + hh * 64 + dd];
                    if (part == 0)
                        qo[((size_t)(b * 12 + hh) * 197 + n) * 64 + dd] = (f16)(v * 0.125f);
                    else if (part == 1)
                        ko[((size_t)(b * 12 + hh) * 197 + n) * 64 + dd] = (f16)v;
                    else
                        vo[((size_t)(b * 12 + hh) * 64 + dd) * 216 + n] = (f16)v;
                }
            }
        }
    } else {
        #pragma unroll
        for (int mi = 0; mi < 4; ++mi)
            #pragma unroll
            for (int r = 0; r < 4; ++r) {
                const int m = m0 + wm * 64 + mi * 16 + ((l >> 4) << 2) + r;
                const int b = m / 197;
                const int s = b_idx[b];
                #pragma unroll
                for (int nj = 0; nj < 4; ++nj) {
                    const int col = n0 + wn * 64 + nj * 16 + (l & 15);
                    fo[(size_t)m * 768 + col] = acc[mi][nj][r] + bp[s * 768 + col];
                }
            }
    }
}

// ---------------- flash attention (MFMA) ----------------
// Block per (b,h), 4 waves; wave w owns q rows [64w, 64w+64) (wave 3: 5 valid, rest
// clamped dups, masked at store). KVBLK=64 (4 tiles; tile 3 cols >196 masked -1e30).
// S frag layout: col j = lane&15, row i = (lane>>4)*4+reg  -> stats lane-group local.
// PV: A = P (LDS, natural [i][j]), B = Vt (global [d][j]) -> O natural (d in lanes).
__global__ __launch_bounds__(256) void attn_mfma(
    const f16* __restrict__ qg, const f16* __restrict__ kg,
    const f16* __restrict__ vtg, const f16* __restrict__ rpbt,
    f16* __restrict__ og)
{
    __shared__ alignas(16) f16 Pl[4][64 * 72];   // per-wave P, stride 144B + XOR swizzle
    const int bh = blockIdx.x;
    const int h  = bh % 12;
    const int t = threadIdx.x, l = t & 63, w = t >> 6;
    const int l15 = l & 15, lg = l >> 4;
    const int wq0 = w * 64;
    char* Pw = (char*)&Pl[w][0];

    const f16* qb  = qg  + (size_t)bh * 197 * 64;
    const f16* kb  = kg  + (size_t)bh * 197 * 64;
    const f16* vtb = vtg + (size_t)bh * 64 * 216;
    const f16* rp  = rpbt + (size_t)h * 197 * 200;

    f16x8 qf[4][2];
    #pragma unroll
    for (int mi = 0; mi < 4; ++mi)
        #pragma unroll
        for (int kk = 0; kk < 2; ++kk) {
            int row = wq0 + mi * 16 + l15; if (row > 196) row = 196;
            qf[mi][kk] = *(const f16x8*)(qb + row * 64 + kk * 32 + lg * 8);
        }

    f32x4 o[4][4] = {};                    // [mi (i-rows)][dj (d-cols)]
    float mst[4][4], lst[4][4];            // [mi][reg]
    #pragma unroll
    for (int a = 0; a < 4; ++a)
        #pragma unroll
        for (int b = 0; b < 4; ++b) { mst[a][b] = -__builtin_huge_valf(); lst[a][b] = 0.f; }

    for (int tt = 0; tt < 4; ++tt) {
        const int j0 = tt * 64;
        f32x4 s[4][4] = {};
        #pragma unroll
        for (int kk = 0; kk < 2; ++kk) {
            f16x8 bk[4];
            #pragma unroll
            for (int nj = 0; nj < 4; ++nj) {
                int jr = j0 + nj * 16 + l15; if (jr > 196) jr = 196;
                bk[nj] = *(const f16x8*)(kb + jr * 64 + kk * 32 + lg * 8);
            }
            #pragma unroll
            for (int mi = 0; mi < 4; ++mi)
                #pragma unroll
                for (int nj = 0; nj < 4; ++nj)
                    s[mi][nj] = MFMA16(qf[mi][kk], bk[nj], s[mi][nj]);
        }
        // + relative-position bias (f16x4 over 4 consecutive i), mask invalid cols
        #pragma unroll
        for (int mi = 0; mi < 4; ++mi) {
            int i0 = wq0 + mi * 16 + lg * 4; if (i0 > 196) i0 = 196;
            #pragma unroll
            for (int nj = 0; nj < 4; ++nj) {
                const int j = j0 + nj * 16 + l15;
                const int jc = (j > 196) ? 196 : j;
                union { uint2 u; f16 hv[4]; } rv;
                rv.u = *(const uint2*)(rp + jc * 200 + i0);
                #pragma unroll
                for (int r = 0; r < 4; ++r) s[mi][nj][r] += (float)rv.hv[r];
                if (j > 196) {
                    #pragma unroll
                    for (int r = 0; r < 4; ++r) s[mi][nj][r] = -1e30f;
                }
            }
        }
        // online softmax per row (stats replicated across the 16-lane group)
        float scB[4][4];
        #pragma unroll
        for (int mi = 0; mi < 4; ++mi)
            #pragma unroll
            for (int r = 0; r < 4; ++r) {
                float cur = fmaxf(fmaxf(s[mi][0][r], s[mi][1][r]),
                                  fmaxf(s[mi][2][r], s[mi][3][r]));
                cur = fmaxf(cur, __shfl_xor(cur, 1, 16));
                cur = fmaxf(cur, __shfl_xor(cur, 2, 16));
                cur = fmaxf(cur, __shfl_xor(cur, 4, 16));
                cur = fmaxf(cur, __shfl_xor(cur, 8, 16));
                const float mo = mst[mi][r];
                const float mn = fmaxf(mo, cur);
                const float sc = __expf(mo - mn);
                mst[mi][r] = mn;
                float rs = 0.f;
                #pragma unroll
                for (int nj = 0; nj < 4; ++nj) {
                    const float p = __expf(s[mi][nj][r] - mn);
                    s[mi][nj][r] = p;
                    rs += p;
                }
                rs += __shfl_xor(rs, 1, 16);
                rs += __shfl_xor(rs, 2, 16);
                rs += __shfl_xor(rs, 4, 16);
                rs += __shfl_xor(rs, 8, 16);
                lst[mi][r] = lst[mi][r] * sc + rs;
                scB[mi][r] = sc;
            }
        #pragma unroll
        for (int mi = 0; mi < 4; ++mi)
            #pragma unroll
            for (int dj = 0; dj < 4; ++dj)
                #pragma unroll
                for (int r = 0; r < 4; ++r)
                    o[mi][dj][r] *= scB[mi][r];
        // P -> LDS fp16 ([i][j], stride 144B, XOR (i&7)<<4)
        #pragma unroll
        for (int mi = 0; mi < 4; ++mi)
            #pragma unroll
            for (int nj = 0; nj < 4; ++nj)
                #pragma unroll
                for (int r = 0; r < 4; ++r) {
                    const int i = mi * 16 + lg * 4 + r;
                    const int j = nj * 16 + l15;
                    *(f16*)(Pw + i * 144 + ((j * 2) ^ ((i & 7) << 4))) = (f16)s[mi][nj][r];
                }
        // PV: O[i][d] += P[i][j] * Vt[d][j]
        #pragma unroll
        for (int kk = 0; kk < 2; ++kk) {
            f16x8 av[4], bpv[4];
            #pragma unroll
            for (int dj = 0; dj < 4; ++dj) {
                int jc = j0 + kk * 32 + lg * 8; if (jc > 208) jc = 208;
                av[dj] = *(const f16x8*)(vtb + (dj * 16 + l15) * 216 + jc);
            }
            #pragma unroll
            for (int mi = 0; mi < 4; ++mi) {
                const int i = mi * 16 + l15;
                bpv[mi] = *(const f16x8*)((const char*)Pw +
                          i * 144 + (((kk * 32 + lg * 8) * 2) ^ ((i & 7) << 4)));
            }
            #pragma unroll
            for (int mi = 0; mi < 4; ++mi)
                #pragma unroll
                for (int dj = 0; dj < 4; ++dj)
                    o[mi][dj] = MFMA16(bpv[mi], av[dj], o[mi][dj]);   // A=P, B=Vt
        }
    }
    // normalize + store (rows masked; lanes = consecutive d -> 32B-coalesced)
    #pragma unroll
    for (int mi = 0; mi < 4; ++mi)
        #pragma unroll
        for (int r = 0; r < 4; ++r) {
            const int n = wq0 + mi * 16 + lg * 4 + r;
            if (n > 196) continue;
            const float linv = 1.0f / lst[mi][r];
            #pragma unroll
            for (int dj = 0; dj < 4; ++dj)
                og[((size_t)bh * 197 + n) * 64 + dj * 16 + l15] =
                    (f16)(o[mi][dj][r] * linv);
        }
}

// ---------------- launcher ----------------
extern "C" void kernel_launch(void* const* d_in, const int* in_sizes, int n_in,
                              void* d_out, int out_size, void* d_ws, size_t ws_size,
                              hipStream_t stream)
{
    const float* x      = (const float*)d_in[0];
    const int*   b_idx  = (const int*)  d_in[1];
    const float* w_qkv  = (const float*)d_in[2];
    const float* q_bias = (const float*)d_in[3];
    const float* k_bias = (const float*)d_in[4];
    const float* v_bias = (const float*)d_in[5];
    const float* table  = (const float*)d_in[6];
    const int*   ridx   = (const int*)  d_in[7];
    const float* w_proj = (const float*)d_in[8];
    const float* b_proj = (const float*)d_in[9];

    char* ws = (char*)d_ws;
    f16* xh     = (f16*)ws;                              // 38,731,776 B (overlaid by oh)
    f16* oh     = xh;                                    // [b][h][n][64] after attn
    f16* kh     = (f16*)(ws + 38731776);                 // 38,731,776 B
    f16* vt     = (f16*)(ws + 77463552);                 // 42,467,328 B [b][h][64][216]
    f16* wqkvh  = (f16*)(ws + 119930880);                //  3,538,944 B
    f16* wprojh = (f16*)(ws + 123469824);                //  1,179,648 B
    f16* rpbt   = (f16*)(ws + 124649472);                //    945,600 B  (tot 125.6 MB)
    f16* qh     = (f16*)d_out;                           // q scratch lives in d_out

    cvt_kernel<<<9456, 256, 0, stream>>>(x, xh, 2420736);
    cvt_kernel<<<864,  256, 0, stream>>>(w_qkv, wqkvh, 221184);
    cvt_kernel<<<288,  256, 0, stream>>>(w_proj, wprojh, 73728);
    rpbt_kernel<<<1847, 256, 0, stream>>>(table, ridx, rpbt);

    mfma_gemm<0><<<dim3(197, 18), 256, 0, stream>>>(
        xh, wqkvh, b_idx, q_bias, k_bias, v_bias, qh, kh, vt, nullptr, nullptr);

    attn_mfma<<<1536, 256, 0, stream>>>(qh, kh, vt, rpbt, oh);

    mfma_gemm<1><<<dim3(197, 6), 256, 0, stream>>>(
        oh, wprojh, b_idx, nullptr, nullptr, nullptr,
        nullptr, nullptr, nullptr, (float*)d_out, b_proj);
}

// Round 7
// 514.001 us; speedup vs baseline: 4.7211x; 1.1920x over previous
//
#include <hip/hip_runtime.h>

// BEiT attention block on MFMA (gfx950). B=128 N=197 C=768 H=12 d=64.
// All GEMM work on v_mfma_f32_16x16x32_f16 (fp16 in, fp32 accum).
// Pipeline:
//   cvt    : x, w_qkv, w_proj -> fp16
//   rpbt   : rel-pos bias gathered to [h][j][i-pad200] fp16
//   gemm<0>: qkv = xh @ wqkvh^T (global_load_lds staging, XCD-swizzled grid);
//            epilogue: +bitfit bias, q*0.125 -> d_out lo, k -> ws, v -> d_out hi
//   vtrans : v [b,h,n,64] -> vt [b,h,64,200] (register 8x8 transpose, coalesced)
//   attn   : flash per (b,h); wave = 64 q rows; K/Vt/rpb streamed from L2
//   gemm<1>: out = oh @ wprojh^T + b_proj -> d_out (f32)
// d_out doubles as scratch: [q f16 38.7M][v f16 38.7M] then overwritten by f32 out.
// ws (122.4 MB): [xh|oh 38.7M][kh 38.7M][vt 39.3M][wqkvh][wprojh][rpbt]

typedef _Float16 f16;
typedef __attribute__((ext_vector_type(8))) _Float16 f16x8;
typedef __attribute__((ext_vector_type(4))) float f32x4;
#define MFMA16(a, b, c) __builtin_amdgcn_mfma_f32_16x16x32_f16(a, b, c, 0, 0, 0)

__device__ __forceinline__ void gld16(const f16* g, f16* l) {
    __builtin_amdgcn_global_load_lds(
        (const __attribute__((address_space(1))) void*)g,
        (__attribute__((address_space(3))) void*)l, 16, 0, 0);
}

// ---------------- fp32 -> fp16 convert (8 elems/thread) ----------------
__global__ __launch_bounds__(256) void cvt_kernel(
    const float* __restrict__ in, f16* __restrict__ out, int n8)
{
    int g = blockIdx.x * 256 + threadIdx.x;
    if (g >= n8) return;
    const float4 a = *(const float4*)(in + (size_t)g * 8);
    const float4 b = *(const float4*)(in + (size_t)g * 8 + 4);
    f16x8 o;
    o[0] = (f16)a.x; o[1] = (f16)a.y; o[2] = (f16)a.z; o[3] = (f16)a.w;
    o[4] = (f16)b.x; o[5] = (f16)b.y; o[6] = (f16)b.z; o[7] = (f16)b.w;
    *(f16x8*)(out + (size_t)g * 8) = o;
}

// ---------------- rpbt[h][j][i(pad 200)] = table[ridx[i][j]][h] ----------------
__global__ __launch_bounds__(256) void rpbt_kernel(
    const float* __restrict__ table, const int* __restrict__ ridx,
    f16* __restrict__ rpbt)
{
    int g = blockIdx.x * 256 + threadIdx.x;
    if (g >= 12 * 197 * 200) return;
    int h   = g / (197 * 200);
    int rem = g - h * 197 * 200;
    int j   = rem / 200;
    int i   = rem - j * 200;
    if (i > 196) i = 196;
    rpbt[g] = (f16)table[ridx[i * 197 + j] * 12 + h];
}

// ---------------- V transpose: vh[b,h,n,64] -> vt[b,h,64,200] ----------------
// Block per (b,h); thread = one 8x8 tile (200 active of 256). Both sides 16B.
__global__ __launch_bounds__(256) void vtrans_kernel(
    const f16* __restrict__ vh, f16* __restrict__ vt)
{
    const int bh = blockIdx.x, t = threadIdx.x;
    const int db = t & 7, nb = t >> 3;
    if (nb > 24) return;
    const f16* src = vh + (size_t)bh * 197 * 64;
    f16* dst = vt + (size_t)bh * 64 * 200;
    f16x8 rin[8];
    #pragma unroll
    for (int r = 0; r < 8; ++r) {
        int n = nb * 8 + r; if (n > 196) n = 196;   // pad cols = dup of 196 (finite)
        rin[r] = *(const f16x8*)(src + n * 64 + db * 8);
    }
    #pragma unroll
    for (int j = 0; j < 8; ++j) {
        f16x8 o;
        #pragma unroll
        for (int r = 0; r < 8; ++r) o[r] = rin[r][j];
        *(f16x8*)(dst + (db * 8 + j) * 200 + nb * 8) = o;
    }
}

// ---------------- MFMA GEMM: C[m][n] = sum_k A[m][k] * W[n][k] ----------------
// 128x128 tile, BK=32, 4 waves (2x2), per-wave 64x64 = 4x4 16x16x32 frags.
// Staging: global_load_lds dwordx4, linear LDS [128 rows][32 halfs] (m97 mirror).
// Grid: 1-D, bijective XCD swizzle, n-minor (A-panel reuse; W L2-resident/XCD).
// MODE 0: A = xh [M][768] -> q(*0.125)+k+v natural.  MODE 1: A = oh [b,h,n,64] -> f32.
template<int MODE, int NBN>
__global__ __launch_bounds__(256) void mfma_gemm(
    const f16* __restrict__ A, const f16* __restrict__ W,
    const int* __restrict__ b_idx,
    const float* __restrict__ bq, const float* __restrict__ bk,
    const float* __restrict__ bv,
    f16* __restrict__ qo, f16* __restrict__ ko, f16* __restrict__ vo,
    float* __restrict__ fo, const float* __restrict__ bp)
{
    __shared__ alignas(16) f16 As[4096];
    __shared__ alignas(16) f16 Bs[4096];
    const int t = threadIdx.x, l = t & 63;
    const int w = t >> 6, wm = w >> 1, wn = w & 1;
    const int l15 = l & 15, lg = l >> 4;

    // bijective XCD swizzle (m204): contiguous v-range per XCD
    const int nwg = gridDim.x, qq = nwg >> 3, rr = nwg & 7;
    const int xcd = blockIdx.x & 7, off = blockIdx.x >> 3;
    const int v = (xcd < rr ? xcd * (qq + 1) : rr * (qq + 1) + (xcd - rr) * qq) + off;
    const int mt = v / NBN, nt = v - mt * NBN;
    const int m0 = mt * 128, n0 = nt * 128;

    // staging: instr (w,i) covers chunks [(w*2+i)*64, +64); chunk c -> row c>>2, slot c&3
    const int c0 = w * 128 + l, c1 = c0 + 64;
    const int row0 = c0 >> 2, sl0 = c0 & 3;
    const int row1 = c1 >> 2, sl1 = c1 & 3;
    f16* AsD = As + w * 1024;              // wave-uniform LDS dests (halfs)
    f16* BsD = Bs + w * 1024;

    const f16* wsrc0 = W + (size_t)(n0 + row0) * 768 + sl0 * 8;
    const f16* wsrc1 = W + (size_t)(n0 + row1) * 768 + sl1 * 8;
    const f16 *asrc0, *asrc1;
    if (MODE == 0) {
        asrc0 = A + (size_t)(m0 + row0) * 768 + sl0 * 8;
        asrc1 = A + (size_t)(m0 + row1) * 768 + sl1 * 8;
    } else {
        int m = m0 + row0, b = m / 197, n = m - b * 197;
        asrc0 = A + ((size_t)(b * 12) * 197 + n) * 64;
        m = m0 + row1; b = m / 197; n = m - b * 197;
        asrc1 = A + ((size_t)(b * 12) * 197 + n) * 64;
    }

    f32x4 acc[4][4] = {};
    for (int kt = 0; kt < 768; kt += 32) {
        __syncthreads();                       // prev compute done
        if (MODE == 0) {
            gld16(asrc0 + kt, AsD);
            gld16(asrc1 + kt, AsD + 512);
        } else {
            const int k00 = kt + sl0 * 8, k01 = kt + sl1 * 8;
            gld16(asrc0 + (k00 >> 6) * 12608 + (k00 & 63), AsD);
            gld16(asrc1 + (k01 >> 6) * 12608 + (k01 & 63), AsD + 512);
        }
        gld16(wsrc0 + kt, BsD);
        gld16(wsrc1 + kt, BsD + 512);
        __syncthreads();                       // vmcnt(0) drained by compiler
        f16x8 af[4], bf[4];
        #pragma unroll
        for (int i = 0; i < 4; ++i) {
            af[i] = *(const f16x8*)(As + (wm * 64 + i * 16 + l15) * 32 + lg * 8);
            bf[i] = *(const f16x8*)(Bs + (wn * 64 + i * 16 + l15) * 32 + lg * 8);
        }
        #pragma unroll
        for (int mi = 0; mi < 4; ++mi)
            #pragma unroll
            for (int nj = 0; nj < 4; ++nj)
                acc[mi][nj] = MFMA16(af[mi], bf[nj], acc[mi][nj]);
    }

    if (MODE == 0) {
        const int part = n0 / 768;                      // 0=q 1=k 2=v (block-uniform)
        const int hh = ((n0 % 768) + wn * 64) >> 6;     // head (wave-uniform)
        const float* bias = (part == 0) ? bq : (part == 1) ? bk : bv;
        f16* outp = (part == 0) ? qo : (part == 1) ? ko : vo;
        const float scale = (part == 0) ? 0.125f : 1.0f;
        #pragma unroll
        for (int mi = 0; mi < 4; ++mi)
            #pragma unroll
            for (int r = 0; r < 4; ++r) {
                const int m = m0 + wm * 64 + mi * 16 + lg * 4 + r;
                const int b = m / 197, n = m - (m / 197) * 197;
                const int s = b_idx[b];
                #pragma unroll
                for (int nj = 0; nj < 4; ++nj) {
                    const int dd = nj * 16 + l15;
                    const float val = acc[mi][nj][r] + bias[s * 768 + hh * 64 + dd];
                    outp[((size_t)(b * 12 + hh) * 197 + n) * 64 + dd] = (f16)(val * scale);
                }
            }
    } else {
        #pragma unroll
        for (int mi = 0; mi < 4; ++mi)
            #pragma unroll
            for (int r = 0; r < 4; ++r) {
                const int m = m0 + wm * 64 + mi * 16 + lg * 4 + r;
                const int b = m / 197;
                const int s = b_idx[b];
                #pragma unroll
                for (int nj = 0; nj < 4; ++nj) {
                    const int col = n0 + wn * 64 + nj * 16 + l15;
                    fo[(size_t)m * 768 + col] = acc[mi][nj][r] + bp[s * 768 + col];
                }
            }
    }
}

// ---------------- flash attention (MFMA) ----------------
// Block per (b,h), 4 waves; wave w owns q rows [64w, 64w+64). KVBLK=64.
// S frag: col j = l&15, row i = (l>>4)*4+reg. PV: A=P (LDS), B=Vt[d][j-pad200].
__global__ __launch_bounds__(256) void attn_mfma(
    const f16* __restrict__ qg, const f16* __restrict__ kg,
    const f16* __restrict__ vtg, const f16* __restrict__ rpbt,
    f16* __restrict__ og)
{
    __shared__ alignas(16) f16 Pl[4][64 * 72];   // per-wave P, stride 144B + XOR swizzle
    const int bh = blockIdx.x;
    const int h  = bh % 12;
    const int t = threadIdx.x, l = t & 63, w = t >> 6;
    const int l15 = l & 15, lg = l >> 4;
    const int wq0 = w * 64;
    char* Pw = (char*)&Pl[w][0];

    const f16* qb  = qg  + (size_t)bh * 197 * 64;
    const f16* kb  = kg  + (size_t)bh * 197 * 64;
    const f16* vtb = vtg + (size_t)bh * 64 * 200;
    const f16* rp  = rpbt + (size_t)h * 197 * 200;

    f16x8 qf[4][2];
    #pragma unroll
    for (int mi = 0; mi < 4; ++mi)
        #pragma unroll
        for (int kk = 0; kk < 2; ++kk) {
            int row = wq0 + mi * 16 + l15; if (row > 196) row = 196;
            qf[mi][kk] = *(const f16x8*)(qb + row * 64 + kk * 32 + lg * 8);
        }

    f32x4 o[4][4] = {};
    float mst[4][4], lst[4][4];
    #pragma unroll
    for (int a = 0; a < 4; ++a)
        #pragma unroll
        for (int b = 0; b < 4; ++b) { mst[a][b] = -__builtin_huge_valf(); lst[a][b] = 0.f; }

    for (int tt = 0; tt < 4; ++tt) {
        const int j0 = tt * 64;
        f32x4 s[4][4] = {};
        #pragma unroll
        for (int kk = 0; kk < 2; ++kk) {
            f16x8 bk[4];
            #pragma unroll
            for (int nj = 0; nj < 4; ++nj) {
                int jr = j0 + nj * 16 + l15; if (jr > 196) jr = 196;
                bk[nj] = *(const f16x8*)(kb + jr * 64 + kk * 32 + lg * 8);
            }
            __builtin_amdgcn_s_setprio(1);
            #pragma unroll
            for (int mi = 0; mi < 4; ++mi)
                #pragma unroll
                for (int nj = 0; nj < 4; ++nj)
                    s[mi][nj] = MFMA16(qf[mi][kk], bk[nj], s[mi][nj]);
            __builtin_amdgcn_s_setprio(0);
        }
        // + rel-pos bias (f16x4 over 4 consecutive i), mask invalid cols
        #pragma unroll
        for (int mi = 0; mi < 4; ++mi) {
            int i0 = wq0 + mi * 16 + lg * 4; if (i0 > 196) i0 = 196;
            #pragma unroll
            for (int nj = 0; nj < 4; ++nj) {
                const int j = j0 + nj * 16 + l15;
                const int jc = (j > 196) ? 196 : j;
                union { uint2 u; f16 hv[4]; } rv;
                rv.u = *(const uint2*)(rp + jc * 200 + i0);
                #pragma unroll
                for (int r = 0; r < 4; ++r) s[mi][nj][r] += (float)rv.hv[r];
                if (j > 196) {
                    #pragma unroll
                    for (int r = 0; r < 4; ++r) s[mi][nj][r] = -1e30f;
                }
            }
        }
        // online softmax per row (stats replicated across 16-lane group)
        float scB[4][4];
        #pragma unroll
        for (int mi = 0; mi < 4; ++mi)
            #pragma unroll
            for (int r = 0; r < 4; ++r) {
                float cur = fmaxf(fmaxf(s[mi][0][r], s[mi][1][r]),
                                  fmaxf(s[mi][2][r], s[mi][3][r]));
                cur = fmaxf(cur, __shfl_xor(cur, 1, 16));
                cur = fmaxf(cur, __shfl_xor(cur, 2, 16));
                cur = fmaxf(cur, __shfl_xor(cur, 4, 16));
                cur = fmaxf(cur, __shfl_xor(cur, 8, 16));
                const float mo = mst[mi][r];
                const float mn = fmaxf(mo, cur);
                const float sc = __expf(mo - mn);
                mst[mi][r] = mn;
                float rs = 0.f;
                #pragma unroll
                for (int nj = 0; nj < 4; ++nj) {
                    const float p = __expf(s[mi][nj][r] - mn);
                    s[mi][nj][r] = p;
                    rs += p;
                }
                rs += __shfl_xor(rs, 1, 16);
                rs += __shfl_xor(rs, 2, 16);
                rs += __shfl_xor(rs, 4, 16);
                rs += __shfl_xor(rs, 8, 16);
                lst[mi][r] = lst[mi][r] * sc + rs;
                scB[mi][r] = sc;
            }
        #pragma unroll
        for (int mi = 0; mi < 4; ++mi)
            #pragma unroll
            for (int dj = 0; dj < 4; ++dj)
                #pragma unroll
                for (int r = 0; r < 4; ++r)
                    o[mi][dj][r] *= scB[mi][r];
        // P -> LDS fp16 ([i][j], stride 144B, XOR (i&7)<<4)
        #pragma unroll
        for (int mi = 0; mi < 4; ++mi)
            #pragma unroll
            for (int nj = 0; nj < 4; ++nj)
                #pragma unroll
                for (int r = 0; r < 4; ++r) {
                    const int i = mi * 16 + lg * 4 + r;
                    const int j = nj * 16 + l15;
                    *(f16*)(Pw + i * 144 + ((j * 2) ^ ((i & 7) << 4))) = (f16)s[mi][nj][r];
                }
        // PV: O[i][d] += P[i][j] * Vt[d][j]
        #pragma unroll
        for (int kk = 0; kk < 2; ++kk) {
            f16x8 av[4], bpv[4];
            #pragma unroll
            for (int dj = 0; dj < 4; ++dj) {
                int jc = j0 + kk * 32 + lg * 8;
                if (jc > 192) jc = 192;          // clamped positions all have P=0
                av[dj] = *(const f16x8*)(vtb + (dj * 16 + l15) * 200 + jc);
            }
            #pragma unroll
            for (int mi = 0; mi < 4; ++mi) {
                const int i = mi * 16 + l15;
                bpv[mi] = *(const f16x8*)((const char*)Pw +
                          i * 144 + (((kk * 32 + lg * 8) * 2) ^ ((i & 7) << 4)));
            }
            __builtin_amdgcn_s_setprio(1);
            #pragma unroll
            for (int mi = 0; mi < 4; ++mi)
                #pragma unroll
                for (int dj = 0; dj < 4; ++dj)
                    o[mi][dj] = MFMA16(bpv[mi], av[dj], o[mi][dj]);
            __builtin_amdgcn_s_setprio(0);
        }
    }
    // normalize + store
    #pragma unroll
    for (int mi = 0; mi < 4; ++mi)
        #pragma unroll
        for (int r = 0; r < 4; ++r) {
            const int n = wq0 + mi * 16 + lg * 4 + r;
            if (n > 196) continue;
            const float linv = 1.0f / lst[mi][r];
            #pragma unroll
            for (int dj = 0; dj < 4; ++dj)
                og[((size_t)bh * 197 + n) * 64 + dj * 16 + l15] =
                    (f16)(o[mi][dj][r] * linv);
        }
}

// ---------------- launcher ----------------
extern "C" void kernel_launch(void* const* d_in, const int* in_sizes, int n_in,
                              void* d_out, int out_size, void* d_ws, size_t ws_size,
                              hipStream_t stream)
{
    const float* x      = (const float*)d_in[0];
    const int*   b_idx  = (const int*)  d_in[1];
    const float* w_qkv  = (const float*)d_in[2];
    const float* q_bias = (const float*)d_in[3];
    const float* k_bias = (const float*)d_in[4];
    const float* v_bias = (const float*)d_in[5];
    const float* table  = (const float*)d_in[6];
    const int*   ridx   = (const int*)  d_in[7];
    const float* w_proj = (const float*)d_in[8];
    const float* b_proj = (const float*)d_in[9];

    char* ws = (char*)d_ws;
    f16* xh     = (f16*)ws;                      // 38,731,776 B (oh overlays after attn)
    f16* oh     = xh;
    f16* kh     = (f16*)(ws + 38731776);         // 38,731,776 B
    f16* vt     = (f16*)(ws + 77463552);         // 39,321,600 B [b,h,64,200]
    f16* wqkvh  = (f16*)(ws + 116785152);        //  3,538,944 B
    f16* wprojh = (f16*)(ws + 120324096);        //  1,179,648 B
    f16* rpbt   = (f16*)(ws + 121503744);        //    945,600 B (total 122.4 MB)
    f16* qh     = (f16*)d_out;                   // d_out scratch: [q f16][v f16]
    f16* vh     = qh + 19365888;

    cvt_kernel<<<9456, 256, 0, stream>>>(x, xh, 2420736);
    cvt_kernel<<<864,  256, 0, stream>>>(w_qkv, wqkvh, 221184);
    cvt_kernel<<<288,  256, 0, stream>>>(w_proj, wprojh, 73728);
    rpbt_kernel<<<1847, 256, 0, stream>>>(table, ridx, rpbt);

    mfma_gemm<0, 18><<<3546, 256, 0, stream>>>(
        xh, wqkvh, b_idx, q_bias, k_bias, v_bias, qh, kh, vh, nullptr, nullptr);

    vtrans_kernel<<<1536, 256, 0, stream>>>(vh, vt);

    attn_mfma<<<1536, 256, 0, stream>>>(qh, kh, vt, rpbt, oh);

    mfma_gemm<1, 6><<<1182, 256, 0, stream>>>(
        oh, wprojh, b_idx, nullptr, nullptr, nullptr,
        nullptr, nullptr, nullptr, (float*)d_out, b_proj);
}

// Round 9
// 468.541 us; speedup vs baseline: 5.1792x; 1.0970x over previous
//
#include <hip/hip_runtime.h>

// BEiT attention block on MFMA (gfx950). B=128 N=197 C=768 H=12 d=64.
// Pipeline:
//   cvt    : x, w_qkv, w_proj -> fp16
//   rpbt32 : rel-pos bias -> [h][j:256][i:256] f32, *log2e, cols j>196 = -1e30 (mask baked)
//   gemm<0>: qkv (global_load_lds staging, XCD swizzle); q scaled by 0.125*log2e
//   vtrans : v [b,h,n,64] -> vt [b,h,64,200]
//   attn   : no-max softmax: P = exp2(QK' + rpb'), row-sum deferred to end
//   gemm<1>: out = oh @ wprojh^T + b_proj -> d_out (f32)
// d_out doubles as scratch: [q f16][v f16]; ws 124.6 MB.

typedef _Float16 f16;
typedef __attribute__((ext_vector_type(8))) _Float16 f16x8;
typedef __attribute__((ext_vector_type(4))) float f32x4;
#define MFMA16(a, b, c) __builtin_amdgcn_mfma_f32_16x16x32_f16(a, b, c, 0, 0, 0)

__device__ __forceinline__ void gld16(const f16* g, f16* l) {
    __builtin_amdgcn_global_load_lds(
        (const __attribute__((address_space(1))) void*)g,
        (__attribute__((address_space(3))) void*)l, 16, 0, 0);
}
__device__ __forceinline__ float fexp2(float x) {   // v_exp_f32 = 2^x
    float r; asm("v_exp_f32 %0, %1" : "=v"(r) : "v"(x)); return r;
}

// ---------------- fp32 -> fp16 convert (8 elems/thread) ----------------
__global__ __launch_bounds__(256) void cvt_kernel(
    const float* __restrict__ in, f16* __restrict__ out, int n8)
{
    int g = blockIdx.x * 256 + threadIdx.x;
    if (g >= n8) return;
    const float4 a = *(const float4*)(in + (size_t)g * 8);
    const float4 b = *(const float4*)(in + (size_t)g * 8 + 4);
    f16x8 o;
    o[0] = (f16)a.x; o[1] = (f16)a.y; o[2] = (f16)a.z; o[3] = (f16)a.w;
    o[4] = (f16)b.x; o[5] = (f16)b.y; o[6] = (f16)b.z; o[7] = (f16)b.w;
    *(f16x8*)(out + (size_t)g * 8) = o;
}

// ------- rpbt32[h][j:256][i:256] = log2e * table[ridx[i][j]][h]; j>196 -> -1e30 -------
__global__ __launch_bounds__(256) void rpbt32_kernel(
    const float* __restrict__ table, const int* __restrict__ ridx,
    float* __restrict__ out)
{
    int g = blockIdx.x * 256 + threadIdx.x;       // 12*256*256 = 786432
    int h = g >> 16, rem = g & 65535;
    int j = rem >> 8, i = rem & 255;
    float v;
    if (j > 196) v = -1e30f;
    else {
        int ic = (i > 196) ? 196 : i;             // pad rows = dup (masked at O store)
        v = table[ridx[ic * 197 + j] * 12 + h] * 1.44269504f;
    }
    out[g] = v;
}

// ---------------- V transpose: vh[b,h,n,64] -> vt[b,h,64,200] ----------------
__global__ __launch_bounds__(256) void vtrans_kernel(
    const f16* __restrict__ vh, f16* __restrict__ vt)
{
    const int bh = blockIdx.x, t = threadIdx.x;
    const int db = t & 7, nb = t >> 3;
    if (nb > 24) return;
    const f16* src = vh + (size_t)bh * 197 * 64;
    f16* dst = vt + (size_t)bh * 64 * 200;
    f16x8 rin[8];
    #pragma unroll
    for (int r = 0; r < 8; ++r) {
        int n = nb * 8 + r; if (n > 196) n = 196;
        rin[r] = *(const f16x8*)(src + n * 64 + db * 8);
    }
    #pragma unroll
    for (int j = 0; j < 8; ++j) {
        f16x8 o;
        #pragma unroll
        for (int r = 0; r < 8; ++r) o[r] = rin[r][j];
        *(f16x8*)(dst + (db * 8 + j) * 200 + nb * 8) = o;
    }
}

// ---------------- MFMA GEMM (unchanged structure from R7) ----------------
template<int MODE, int NBN>
__global__ __launch_bounds__(256) void mfma_gemm(
    const f16* __restrict__ A, const f16* __restrict__ W,
    const int* __restrict__ b_idx,
    const float* __restrict__ bq, const float* __restrict__ bk,
    const float* __restrict__ bv,
    f16* __restrict__ qo, f16* __restrict__ ko, f16* __restrict__ vo,
    float* __restrict__ fo, const float* __restrict__ bp)
{
    __shared__ alignas(16) f16 As[4096];
    __shared__ alignas(16) f16 Bs[4096];
    const int t = threadIdx.x, l = t & 63;
    const int w = t >> 6, wm = w >> 1, wn = w & 1;
    const int l15 = l & 15, lg = l >> 4;

    const int nwg = gridDim.x, qq = nwg >> 3, rr = nwg & 7;
    const int xcd = blockIdx.x & 7, off = blockIdx.x >> 3;
    const int v = (xcd < rr ? xcd * (qq + 1) : rr * (qq + 1) + (xcd - rr) * qq) + off;
    const int mt = v / NBN, nt = v - mt * NBN;
    const int m0 = mt * 128, n0 = nt * 128;

    const int c0 = w * 128 + l, c1 = c0 + 64;
    const int row0 = c0 >> 2, sl0 = c0 & 3;
    const int row1 = c1 >> 2, sl1 = c1 & 3;
    f16* AsD = As + w * 1024;
    f16* BsD = Bs + w * 1024;

    const f16* wsrc0 = W + (size_t)(n0 + row0) * 768 + sl0 * 8;
    const f16* wsrc1 = W + (size_t)(n0 + row1) * 768 + sl1 * 8;
    const f16 *asrc0, *asrc1;
    if (MODE == 0) {
        asrc0 = A + (size_t)(m0 + row0) * 768 + sl0 * 8;
        asrc1 = A + (size_t)(m0 + row1) * 768 + sl1 * 8;
    } else {
        int m = m0 + row0, b = m / 197, n = m - b * 197;
        asrc0 = A + ((size_t)(b * 12) * 197 + n) * 64;
        m = m0 + row1; b = m / 197; n = m - b * 197;
        asrc1 = A + ((size_t)(b * 12) * 197 + n) * 64;
    }

    f32x4 acc[4][4] = {};
    for (int kt = 0; kt < 768; kt += 32) {
        __syncthreads();
        if (MODE == 0) {
            gld16(asrc0 + kt, AsD);
            gld16(asrc1 + kt, AsD + 512);
        } else {
            const int k00 = kt + sl0 * 8, k01 = kt + sl1 * 8;
            gld16(asrc0 + (k00 >> 6) * 12608 + (k00 & 63), AsD);
            gld16(asrc1 + (k01 >> 6) * 12608 + (k01 & 63), AsD + 512);
        }
        gld16(wsrc0 + kt, BsD);
        gld16(wsrc1 + kt, BsD + 512);
        __syncthreads();
        f16x8 af[4], bf[4];
        #pragma unroll
        for (int i = 0; i < 4; ++i) {
            af[i] = *(const f16x8*)(As + (wm * 64 + i * 16 + l15) * 32 + lg * 8);
            bf[i] = *(const f16x8*)(Bs + (wn * 64 + i * 16 + l15) * 32 + lg * 8);
        }
        #pragma unroll
        for (int mi = 0; mi < 4; ++mi)
            #pragma unroll
            for (int nj = 0; nj < 4; ++nj)
                acc[mi][nj] = MFMA16(af[mi], bf[nj], acc[mi][nj]);
    }

    if (MODE == 0) {
        const int part = n0 / 768;
        const int hh = ((n0 % 768) + wn * 64) >> 6;
        const float* bias = (part == 0) ? bq : (part == 1) ? bk : bv;
        f16* outp = (part == 0) ? qo : (part == 1) ? ko : vo;
        const float scale = (part == 0) ? 0.18033688f : 1.0f;   // 0.125 * log2(e)
        #pragma unroll
        for (int mi = 0; mi < 4; ++mi)
            #pragma unroll
            for (int r = 0; r < 4; ++r) {
                const int m = m0 + wm * 64 + mi * 16 + lg * 4 + r;
                const int b = m / 197, n = m - (m / 197) * 197;
                const int s = b_idx[b];
                #pragma unroll
                for (int nj = 0; nj < 4; ++nj) {
                    const int dd = nj * 16 + l15;
                    const float val = acc[mi][nj][r] + bias[s * 768 + hh * 64 + dd];
                    outp[((size_t)(b * 12 + hh) * 197 + n) * 64 + dd] = (f16)(val * scale);
                }
            }
    } else {
        #pragma unroll
        for (int mi = 0; mi < 4; ++mi)
            #pragma unroll
            for (int r = 0; r < 4; ++r) {
                const int m = m0 + wm * 64 + mi * 16 + lg * 4 + r;
                const int b = m / 197;
                const int s = b_idx[b];
                #pragma unroll
                for (int nj = 0; nj < 4; ++nj) {
                    const int col = n0 + wn * 64 + nj * 16 + l15;
                    fo[(size_t)m * 768 + col] = acc[mi][nj][r] + bp[s * 768 + col];
                }
            }
    }
}

// ---------------- flash attention v2 (no-max softmax, deferred row-sum) ----------------
// Grid = 2 blocks per (b,h); block = 4 waves x 32 q-rows. wave with wq0>196 exits.
// S-init = rpb32 float4 (col mask baked as -1e30). P = exp2(S) -> LDS fp16 (swizzled).
// PV: A = P rows, B = Vt. Row-sums accumulated per-thread, one shfl-reduce at end.
__global__ __launch_bounds__(256) void attn_mfma(
    const f16* __restrict__ qg, const f16* __restrict__ kg,
    const f16* __restrict__ vtg, const float* __restrict__ rpb32,
    f16* __restrict__ og)
{
    __shared__ alignas(16) f16 Pl[4][32 * 72];   // per-wave P: 32 rows x 64 cols, 144B stride
    const int blk = blockIdx.x;
    const int bh = blk >> 1, half = blk & 1;
    const int h = bh % 12;
    const int t = threadIdx.x, l = t & 63, w = t >> 6;
    const int l15 = l & 15, lg = l >> 4;
    const int wq0 = half * 128 + w * 32;
    if (wq0 > 196) return;                        // wave-uniform exit (no barriers used)
    const int nmi = (wq0 <= 180) ? 2 : 1;         // wq0=192 -> 1 fragment
    char* Pw = (char*)&Pl[w][0];
    const int swzW = (lg >= 2) ? 32 : 0;          // ((i_loc>>3)&1)<<5 for stores
    const int swzR = ((l15 >> 3) & 1) << 5;       // for b128 reads (i_loc = mi*16+l15)

    const f16* qb  = qg  + (size_t)bh * 197 * 64;
    const f16* kb  = kg  + (size_t)bh * 197 * 64;
    const f16* vtb = vtg + (size_t)bh * 64 * 200;
    const float* rp = rpb32 + (size_t)h * 65536;

    f16x8 qf[2][2];
    #pragma unroll
    for (int mi = 0; mi < 2; ++mi)
        #pragma unroll
        for (int kk = 0; kk < 2; ++kk)
            qf[mi][kk] = *(const f16x8*)(qb + (wq0 + mi * 16 + l15) * 64 + kk * 32 + lg * 8);

    f32x4 o[2][4] = {};
    float lsum[2][4] = {};

    for (int tt = 0; tt < 4; ++tt) {
        const int j0 = tt * 64;
        const int njc = (tt == 3) ? 1 : 4;
        // K fragments (reads past row 196 land in valid ws memory; masked by rpb -1e30)
        f16x8 bk[4][2];
        #pragma unroll
        for (int nj = 0; nj < 4; ++nj) {
            if (nj >= njc) break;
            #pragma unroll
            for (int kk = 0; kk < 2; ++kk)
                bk[nj][kk] = *(const f16x8*)(kb + (j0 + nj * 16 + l15) * 64 + kk * 32 + lg * 8);
        }
        #pragma unroll
        for (int mi = 0; mi < 2; ++mi) {
            if (mi >= nmi) break;
            const int i0 = wq0 + mi * 16 + lg * 4;
            f32x4 s[4];
            #pragma unroll
            for (int nj = 0; nj < 4; ++nj) {
                if (nj >= njc) break;
                s[nj] = *(const f32x4*)(rp + (j0 + nj * 16 + l15) * 256 + i0);
            }
            __builtin_amdgcn_s_setprio(1);
            #pragma unroll
            for (int kk = 0; kk < 2; ++kk)
                #pragma unroll
                for (int nj = 0; nj < 4; ++nj) {
                    if (nj >= njc) break;
                    s[nj] = MFMA16(qf[mi][kk], bk[nj][kk], s[nj]);
                }
            __builtin_amdgcn_s_setprio(0);
            // P = exp2(S); accumulate row-sum; store fp16 to LDS (conflict-free swizzle)
            #pragma unroll
            for (int nj = 0; nj < 4; ++nj) {
                if (nj >= njc) break;
                #pragma unroll
                for (int r = 0; r < 4; ++r) {
                    const float p = fexp2(s[nj][r]);
                    lsum[mi][r] += p;
                    const int iloc = mi * 16 + lg * 4 + r;
                    const int jl = nj * 16 + l15;
                    *(f16*)(Pw + iloc * 144 + ((jl * 2) ^ swzW)) = (f16)p;
                }
            }
        }
        if (tt == 3) {          // zero local cols 16-31 so PV kk=0 reads P=0 there
            #pragma unroll
            for (int mi = 0; mi < 2; ++mi) {
                if (mi >= nmi) break;
                #pragma unroll
                for (int r = 0; r < 4; ++r) {
                    const int iloc = mi * 16 + lg * 4 + r;
                    const int jl = 16 + l15;
                    *(f16*)(Pw + iloc * 144 + ((jl * 2) ^ swzW)) = (f16)0.f;
                }
            }
        }
        // PV: O[i][d] += P[i][j] * Vt[d][j]
        const int kkmax = (tt == 3) ? 1 : 2;
        #pragma unroll
        for (int kk = 0; kk < 2; ++kk) {
            if (kk >= kkmax) break;
            f16x8 av[4], bpv[2];
            #pragma unroll
            for (int dj = 0; dj < 4; ++dj)
                av[dj] = *(const f16x8*)(vtb + (dj * 16 + l15) * 200 + j0 + kk * 32 + lg * 8);
            #pragma unroll
            for (int mi = 0; mi < 2; ++mi) {
                if (mi >= nmi) break;
                const int iloc = mi * 16 + l15;
                bpv[mi] = *(const f16x8*)(Pw + iloc * 144 + (((kk * 32 + lg * 8) * 2) ^ swzR));
            }
            __builtin_amdgcn_s_setprio(1);
            #pragma unroll
            for (int mi = 0; mi < 2; ++mi) {
                if (mi >= nmi) break;
                #pragma unroll
                for (int dj = 0; dj < 4; ++dj)
                    o[mi][dj] = MFMA16(bpv[mi], av[dj], o[mi][dj]);
            }
            __builtin_amdgcn_s_setprio(0);
        }
    }
    // one row-sum reduce + normalize + store
    #pragma unroll
    for (int mi = 0; mi < 2; ++mi) {
        if (mi >= nmi) break;
        #pragma unroll
        for (int r = 0; r < 4; ++r) {
            float rs = lsum[mi][r];
            rs += __shfl_xor(rs, 1, 16);
            rs += __shfl_xor(rs, 2, 16);
            rs += __shfl_xor(rs, 4, 16);
            rs += __shfl_xor(rs, 8, 16);
            const int n = wq0 + mi * 16 + lg * 4 + r;
            if (n > 196) continue;
            const float linv = 1.0f / rs;
            #pragma unroll
            for (int dj = 0; dj < 4; ++dj)
                og[((size_t)bh * 197 + n) * 64 + dj * 16 + l15] =
                    (f16)(o[mi][dj][r] * linv);
        }
    }
}

// ---------------- launcher ----------------
extern "C" void kernel_launch(void* const* d_in, const int* in_sizes, int n_in,
                              void* d_out, int out_size, void* d_ws, size_t ws_size,
                              hipStream_t stream)
{
    const float* x      = (const float*)d_in[0];
    const int*   b_idx  = (const int*)  d_in[1];
    const float* w_qkv  = (const float*)d_in[2];
    const float* q_bias = (const float*)d_in[3];
    const float* k_bias = (const float*)d_in[4];
    const float* v_bias = (const float*)d_in[5];
    const float* table  = (const float*)d_in[6];
    const int*   ridx   = (const int*)  d_in[7];
    const float* w_proj = (const float*)d_in[8];
    const float* b_proj = (const float*)d_in[9];

    char* ws = (char*)d_ws;
    f16* xh     = (f16*)ws;                      // 38,731,776 B (oh overlays after attn)
    f16* oh     = xh;
    f16* kh     = (f16*)(ws + 38731776);         // 38,731,776 B
    f16* vt     = (f16*)(ws + 77463552);         // 39,321,600 B [b,h,64,200]
    f16* wqkvh  = (f16*)(ws + 116785152);        //  3,538,944 B
    f16* wprojh = (f16*)(ws + 120324096);        //  1,179,648 B
    float* rpb32= (float*)(ws + 121503744);      //  3,145,728 B (total 124.6 MB)
    f16* qh     = (f16*)d_out;                   // d_out scratch: [q f16][v f16]
    f16* vh     = qh + 19365888;

    cvt_kernel<<<9456, 256, 0, stream>>>(x, xh, 2420736);
    cvt_kernel<<<864,  256, 0, stream>>>(w_qkv, wqkvh, 221184);
    cvt_kernel<<<288,  256, 0, stream>>>(w_proj, wprojh, 73728);
    rpbt32_kernel<<<3072, 256, 0, stream>>>(table, ridx, rpb32);

    mfma_gemm<0, 18><<<3546, 256, 0, stream>>>(
        xh, wqkvh, b_idx, q_bias, k_bias, v_bias, qh, kh, vh, nullptr, nullptr);

    vtrans_kernel<<<1536, 256, 0, stream>>>(vh, vt);

    attn_mfma<<<3072, 256, 0, stream>>>(qh, kh, vt, rpb32, oh);

    mfma_gemm<1, 6><<<1182, 256, 0, stream>>>(
        oh, wprojh, b_idx, nullptr, nullptr, nullptr,
        nullptr, nullptr, nullptr, (float*)d_out, b_proj);
}